// Round 1
// baseline (1450.936 us; speedup 1.0000x reference)
//
#include <hip/hip_runtime.h>
#include <hip/hip_bf16.h>
#include <stdint.h>

// Grouped GEMM (MoE experts): out[t, n] = sum_k x[t,k] * w[e(t), n, k] + bias[e(t), n]
// fp32 in/out, bf16 MFMA compute (threshold permits bf16; ~15x error margin).
//
// Tile: BM=128 x BN=128, BK=64, 256 threads (4 waves, each 64x64 via 4x4
// frags of mfma_f32_16x16x32_bf16). fp32->bf16 conversion fused into LDS
// staging (v_perm pack, round-half-up). LDS rows padded to 72 bf16
// (144 B = 9*16B) -> 16B-aligned ds_read_b128, uniform bank use.

#define BM 128
#define BN 128
#define BK 64
#define LDK 72   // padded LDS row length in bf16 elements

typedef short v8s __attribute__((ext_vector_type(8)));
typedef float v4f __attribute__((ext_vector_type(4)));

static __device__ __forceinline__ uint32_t pk_bf16(float lo, float hi) {
    union { float f; uint32_t u; } a, b;
    a.f = lo; b.f = hi;
    // round-half-up to nearest bf16, pack two: dest = [lo.hi16, hi.hi16]
    return __builtin_amdgcn_perm(b.u + 0x8000u, a.u + 0x8000u, 0x07060302u);
}

__global__ __launch_bounds__(256, 2)
void Experts_Cute_54580444398293_kernel(const float* __restrict__ X,
                                        const float* __restrict__ W,
                                        const float* __restrict__ Bias,
                                        const int* __restrict__ counts,
                                        float* __restrict__ Out,
                                        int T, int E, int K, int N) {
    const int nt = blockIdx.x;   // N-tile (fast-varying: consecutive blocks share A-tile via L2/L3)
    const int mt = blockIdx.y;   // global M-tile index across all experts

    // ---- resolve expert / row range for this M-tile (wave-uniform scan) ----
    int e = -1, row0 = 0, rows = 0;
    {
        int tacc = 0, off = 0;
        for (int i = 0; i < E; ++i) {
            int c = counts[i];
            int ti = (c + BM - 1) / BM;
            if (mt < tacc + ti) {
                e = i;
                int local = mt - tacc;
                row0 = off + local * BM;
                rows = c - local * BM;
                if (rows > BM) rows = BM;
                break;
            }
            tacc += ti;
            off += c;
        }
    }
    if (e < 0) return;   // padding block (worst-case grid), uniform exit

    __shared__ __align__(16) short As[BM * LDK];
    __shared__ __align__(16) short Bs[BM * LDK];

    const int tid = threadIdx.x;

    // staging assignment: lane covers one float4; 16 lanes = one full row's
    // 64 floats (256B contiguous per row -> good coalescing)
    const int srow  = tid >> 4;         // 0..15
    const int scol4 = (tid & 15) * 4;   // float offset within BK

    // compute assignment
    const int lane = tid & 63;
    const int wv   = tid >> 6;          // 0..3
    const int wm   = (wv >> 1) * 64;    // wave row offset in tile
    const int wn   = (wv & 1) * 64;     // wave col offset in tile
    const int l16  = lane & 15;
    const int quad = lane >> 4;

    v4f acc[4][4];
#pragma unroll
    for (int i = 0; i < 4; ++i)
#pragma unroll
        for (int j = 0; j < 4; ++j)
            acc[i][j] = (v4f){0.f, 0.f, 0.f, 0.f};

    const float* Wtile = W + ((size_t)e * N + (size_t)nt * BN) * K;
    const int KT = K / BK;

    for (int kt = 0; kt < KT; ++kt) {
        const int k0 = kt * BK;

        // ---- stage A (x): 128 rows x 64 cols fp32 -> bf16 LDS ----
        {
            v4f ra[8];
            const float* Xp = X + k0 + scol4;
#pragma unroll
            for (int p = 0; p < 8; ++p) {
                int gr = row0 + p * 16 + srow;
                if (gr < T) ra[p] = *(const v4f*)(Xp + (size_t)gr * K);
                else        ra[p] = (v4f){0.f, 0.f, 0.f, 0.f};
            }
#pragma unroll
            for (int p = 0; p < 8; ++p) {
                int r = p * 16 + srow;
                uint32_t w0 = pk_bf16(ra[p].x, ra[p].y);
                uint32_t w1 = pk_bf16(ra[p].z, ra[p].w);
                uint2* dst = (uint2*)&As[r * LDK + scol4];
                *dst = make_uint2(w0, w1);
            }
        }
        // ---- stage B (w): 128 rows (n) x 64 cols (k) fp32 -> bf16 LDS ----
        {
            v4f rb[8];
            const float* Wp = Wtile + k0 + scol4;
#pragma unroll
            for (int p = 0; p < 8; ++p) {
                int r = p * 16 + srow;
                rb[p] = *(const v4f*)(Wp + (size_t)r * K);
            }
#pragma unroll
            for (int p = 0; p < 8; ++p) {
                int r = p * 16 + srow;
                uint32_t w0 = pk_bf16(rb[p].x, rb[p].y);
                uint32_t w1 = pk_bf16(rb[p].z, rb[p].w);
                uint2* dst = (uint2*)&Bs[r * LDK + scol4];
                *dst = make_uint2(w0, w1);
            }
        }
        __syncthreads();

        // ---- MFMA over this K-tile: 2 k-steps of 32 ----
#pragma unroll
        for (int ks = 0; ks < 2; ++ks) {
            const int koff = ks * 32 + quad * 8;
            v8s af[4], bf[4];
#pragma unroll
            for (int i = 0; i < 4; ++i)
                af[i] = *(const v8s*)&As[(wm + i * 16 + l16) * LDK + koff];
#pragma unroll
            for (int i = 0; i < 4; ++i)
                bf[i] = *(const v8s*)&Bs[(wn + i * 16 + l16) * LDK + koff];
#pragma unroll
            for (int mi = 0; mi < 4; ++mi)
#pragma unroll
                for (int ni = 0; ni < 4; ++ni)
                    acc[mi][ni] = __builtin_amdgcn_mfma_f32_16x16x32_bf16(
                        af[mi], bf[ni], acc[mi][ni], 0, 0, 0);
        }
        if (kt + 1 < KT) __syncthreads();
    }

    // ---- epilogue: C/D layout col=lane&15, row=quad*4+reg ----
#pragma unroll
    for (int ni = 0; ni < 4; ++ni) {
        const int col = nt * BN + wn + ni * 16 + l16;
        const float bv = Bias[(size_t)e * N + col];
#pragma unroll
        for (int mi = 0; mi < 4; ++mi) {
            const int rbase = wm + mi * 16 + quad * 4;
#pragma unroll
            for (int rr = 0; rr < 4; ++rr) {
                const int lr = rbase + rr;
                if (lr < rows)
                    Out[(size_t)(row0 + lr) * N + col] = acc[mi][ni][rr] + bv;
            }
        }
    }
}

extern "C" void kernel_launch(void* const* d_in, const int* in_sizes, int n_in,
                              void* d_out, int out_size, void* d_ws, size_t ws_size,
                              hipStream_t stream) {
    const float* X      = (const float*)d_in[0];
    const int*   counts = (const int*)d_in[1];
    const float* W      = (const float*)d_in[2];
    const float* Bias   = (const float*)d_in[3];
    float* Out = (float*)d_out;

    const int E = in_sizes[1];
    const int N = in_sizes[3] / E;                 // D_OUT
    const int K = in_sizes[2] / in_sizes[3];       // D_IN
    const int T = in_sizes[0] / K;

    // worst-case M-tiles: sum_e ceil(c_e/BM) <= T/BM + E
    const int mtiles = (T + BM - 1) / BM + E;
    dim3 grid(N / BN, mtiles);
    Experts_Cute_54580444398293_kernel<<<grid, 256, 0, stream>>>(
        X, W, Bias, counts, Out, T, E, K, N);
}